// Round 3
// baseline (983.870 us; speedup 1.0000x reference)
//
#include <hip/hip_runtime.h>
#include <cstdint>
#include <cstddef>

#define INP 2048
#define EMB 512
#define NHEAD 2
#define BSZ 16
#define SEQ 1024
#define LAMBDA 10.0f

typedef __attribute__((ext_vector_type(8))) short bf16x8;
typedef __attribute__((ext_vector_type(4))) float f32x4;
typedef __attribute__((ext_vector_type(16))) float f32x16;

__device__ __forceinline__ short f2bf(float x) {
    union { float f; unsigned u; } v; v.f = x;
    unsigned r = v.u + 0x7fffu + ((v.u >> 16) & 1u);   // RTN-even
    return (short)(r >> 16);
}
__device__ __forceinline__ float bf2f(short h) {
    union { unsigned u; float f; } v; v.u = ((unsigned)(unsigned short)h) << 16;
    return v.f;
}
__device__ __forceinline__ void g2lds16(const void* g, void* l) {
    __builtin_amdgcn_global_load_lds(
        (const __attribute__((address_space(1))) unsigned int*)g,
        (__attribute__((address_space(3))) unsigned int*)l, 16, 0, 0);
}

// ---------------------------------------------------------------------------
__global__ __launch_bounds__(256) void zero_kernel(float* __restrict__ p, int n) {
    int i = blockIdx.x * 256 + threadIdx.x;
    if (i < n) p[i] = 0.f;
}

// ---------------------------------------------------------------------------
// Transpose+convert: src slab [INP][L] fp32 -> out slab [L][INP] bf16 hi/lo.
// ---------------------------------------------------------------------------
__global__ __launch_bounds__(256) void conv_t(const float* __restrict__ src,
                                              short* __restrict__ hi,
                                              short* __restrict__ lo, int L) {
    const int l0 = blockIdx.x * 32;
    const int d0 = blockIdx.y * 32;
    const float* s = src + (size_t)blockIdx.z * INP * L;
    const size_t obase = (size_t)blockIdx.z * INP * L;

    __shared__ float t[32][33];
    const int tid = threadIdx.x;
    const int r  = tid >> 3;
    const int c4 = (tid & 7) * 4;

    float4 v = *(const float4*)&s[(size_t)(d0 + r) * L + l0 + c4];
    t[r][c4 + 0] = v.x; t[r][c4 + 1] = v.y; t[r][c4 + 2] = v.z; t[r][c4 + 3] = v.w;
    __syncthreads();

    short4 h4, l4;
    float x;
    x = t[c4 + 0][r]; h4.x = f2bf(x); l4.x = f2bf(x - bf2f(h4.x));
    x = t[c4 + 1][r]; h4.y = f2bf(x); l4.y = f2bf(x - bf2f(h4.y));
    x = t[c4 + 2][r]; h4.z = f2bf(x); l4.z = f2bf(x - bf2f(h4.z));
    x = t[c4 + 3][r]; h4.w = f2bf(x); l4.w = f2bf(x - bf2f(h4.w));
    const size_t o = obase + (size_t)(l0 + r) * INP + d0 + c4;
    *(short4*)&hi[o] = h4;
    *(short4*)&lo[o] = l4;
}

// ---------------------------------------------------------------------------
// Split-bf16 MFMA projection, 32x32x16 shape, XCD-swizzled 1D grid (512).
// ---------------------------------------------------------------------------
__global__ __launch_bounds__(256) void proj_mfma(
    const short* __restrict__ Ahg, const short* __restrict__ Alg,
    const short* __restrict__ Bhg, const short* __restrict__ Blg,
    const float* __restrict__ bias, float* __restrict__ Q, int im, int bbase) {
    const int bid = blockIdx.x;
    const int xcd = bid & 7;
    const int s   = bid >> 3;          // 0..63
    const int zl  = xcd * 2 + (s >> 5);
    const int t2  = s & 31;
    const int et  = t2 & 3;            // e-tile inner: A-tile L2 reuse x4
    const int lt  = t2 >> 2;
    const int l0 = lt * 128;
    const int e0 = et * 128;
    const int h    = zl >> 3;
    const int bloc = zl & 7;
    const int z = (im * NHEAD + h) * BSZ + bbase + bloc;

    const short* __restrict__ Ah = Ahg + (size_t)bloc * SEQ * INP;
    const short* __restrict__ Al = Alg + (size_t)bloc * SEQ * INP;
    const short* __restrict__ Bh = Bhg + (size_t)h * EMB * INP;
    const short* __restrict__ Bl = Blg + (size_t)h * EMB * INP;

    __shared__ short sAh[128 * 32], sAl[128 * 32], sBh[128 * 32], sBl[128 * 32];

    const int tid  = threadIdx.x;
    const int lane = tid & 63;
    const int wid  = tid >> 6;
    const int srow = lane >> 2;
    const int scol = (lane & 3) * 8;
    const int wm = (wid & 1) * 64;
    const int wn = (wid >> 1) * 64;
    const int fm = lane & 31;
    const int fko = (lane >> 5) * 8;

    f32x16 acc[2][2];
#pragma unroll
    for (int i = 0; i < 2; i++)
#pragma unroll
        for (int j = 0; j < 2; j++)
#pragma unroll
            for (int r = 0; r < 16; r++) acc[i][j][r] = 0.f;

    for (int k0 = 0; k0 < INP; k0 += 32) {
        __syncthreads();
#pragma unroll
        for (int u = 0; u < 2; u++) {
            const int unit = wid * 2 + u;
            const int row  = unit * 16 + srow;
            const size_t ga = (size_t)(l0 + row) * INP + k0 + scol;
            const size_t gb = (size_t)(e0 + row) * INP + k0 + scol;
            const int lo_off = unit * 512;
            g2lds16(Ah + ga, sAh + lo_off);
            g2lds16(Al + ga, sAl + lo_off);
            g2lds16(Bh + gb, sBh + lo_off);
            g2lds16(Bl + gb, sBl + lo_off);
        }
        __syncthreads();

        bf16x8 afh[2][2], afl[2][2], bfh[2][2], bfl[2][2];
#pragma unroll
        for (int i = 0; i < 2; i++)
#pragma unroll
            for (int ks = 0; ks < 2; ks++) {
                const int ra = (wm + i * 32 + fm) * 32 + ks * 16 + fko;
                afh[i][ks] = *(const bf16x8*)&sAh[ra];
                afl[i][ks] = *(const bf16x8*)&sAl[ra];
                const int rb = (wn + i * 32 + fm) * 32 + ks * 16 + fko;
                bfh[i][ks] = *(const bf16x8*)&sBh[rb];
                bfl[i][ks] = *(const bf16x8*)&sBl[rb];
            }
#pragma unroll
        for (int ks = 0; ks < 2; ks++)
#pragma unroll
            for (int i = 0; i < 2; i++)
#pragma unroll
                for (int j = 0; j < 2; j++) {
                    acc[i][j] = __builtin_amdgcn_mfma_f32_32x32x16_bf16(afh[i][ks], bfh[j][ks], acc[i][j], 0, 0, 0);
                    acc[i][j] = __builtin_amdgcn_mfma_f32_32x32x16_bf16(afh[i][ks], bfl[j][ks], acc[i][j], 0, 0, 0);
                    acc[i][j] = __builtin_amdgcn_mfma_f32_32x32x16_bf16(afl[i][ks], bfh[j][ks], acc[i][j], 0, 0, 0);
                }
    }

    float* __restrict__ Qz = Q + (size_t)z * SEQ * EMB;
    float bj[2];
#pragma unroll
    for (int j = 0; j < 2; j++) bj[j] = bias[h * EMB + e0 + wn + j * 32 + fm];
    const int rhalf = (lane >> 5) * 4;
#pragma unroll
    for (int i = 0; i < 2; i++)
#pragma unroll
        for (int r = 0; r < 16; r++) {
            const int row = l0 + wm + i * 32 + (r & 3) + 8 * (r >> 2) + rhalf;
#pragma unroll
            for (int j = 0; j < 2; j++) {
                const int col = e0 + wn + j * 32 + fm;
                Qz[(size_t)row * EMB + col] = acc[i][j][r] + bj[j];
            }
        }
}

// ---------------------------------------------------------------------------
// Row L2-norm of Q (fp32), fold LAMBDA into image-1 slabs, emit bf16 hi/lo.
// ---------------------------------------------------------------------------
__global__ __launch_bounds__(64) void norm_split(const float* __restrict__ Q,
                                                 short* __restrict__ Qhi,
                                                 short* __restrict__ Qlo) {
    const int z = blockIdx.y;
    const size_t row = (size_t)z * SEQ + blockIdx.x;
    const float* p = Q + row * EMB;
    const int lane = threadIdx.x;

    float4 a = *(const float4*)&p[lane * 8];
    float4 b = *(const float4*)&p[lane * 8 + 4];
    float s = a.x * a.x + a.y * a.y + a.z * a.z + a.w * a.w
            + b.x * b.x + b.y * b.y + b.z * b.z + b.w * b.w;
#pragma unroll
    for (int o = 32; o > 0; o >>= 1) s += __shfl_xor(s, o);
    float scale = 1.f / fmaxf(sqrtf(s), 1e-12f);
    if (z < NHEAD * BSZ) scale *= LAMBDA;

    float v[8] = {a.x * scale, a.y * scale, a.z * scale, a.w * scale,
                  b.x * scale, b.y * scale, b.z * scale, b.w * scale};
    short hv[8], lv[8];
#pragma unroll
    for (int q = 0; q < 8; q++) {
        hv[q] = f2bf(v[q]);
        lv[q] = f2bf(v[q] - bf2f(hv[q]));
    }
    short4 h0 = {hv[0], hv[1], hv[2], hv[3]}, h1 = {hv[4], hv[5], hv[6], hv[7]};
    short4 l0v = {lv[0], lv[1], lv[2], lv[3]}, l1v = {lv[4], lv[5], lv[6], lv[7]};
    *(short4*)&Qhi[row * EMB + lane * 8]     = h0;
    *(short4*)&Qhi[row * EMB + lane * 8 + 4] = h1;
    *(short4*)&Qlo[row * EMB + lane * 8]     = l0v;
    *(short4*)&Qlo[row * EMB + lane * 8 + 4] = l1v;
}

// ---------------------------------------------------------------------------
// Split-bf16 MFMA attention, 32x32x16 shape. E stored as bf16; Z sums use the
// bf16-rounded values (numerator/denominator self-consistency).
// 1D grid 2048, XCD-swizzled: each XCD owns 4 hb slabs (~4MB working set).
// ---------------------------------------------------------------------------
__global__ __launch_bounds__(256) void attn_mfma(
    const short* __restrict__ Qhi, const short* __restrict__ Qlo,
    short* __restrict__ E, float* __restrict__ Zr, float* __restrict__ Zc) {
    const int bid = blockIdx.x;
    const int xcd = bid & 7;
    const int s   = bid >> 3;            // 0..255
    const int hb  = xcd * 4 + (s >> 6);
    const int t   = s & 63;
    const int lt  = t & 7;               // l-tile inner: m-tile L2 reuse x8
    const int mt  = t >> 3;
    const int l0 = lt * 128;
    const int m0 = mt * 128;

    const short* __restrict__ Ah = Qhi + (size_t)hb * SEQ * EMB;
    const short* __restrict__ Al = Qlo + (size_t)hb * SEQ * EMB;
    const short* __restrict__ Bh = Qhi + (size_t)(NHEAD * BSZ + hb) * SEQ * EMB;
    const short* __restrict__ Bl = Qlo + (size_t)(NHEAD * BSZ + hb) * SEQ * EMB;

    __shared__ short sAh[128 * 32], sAl[128 * 32], sBh[128 * 32], sBl[128 * 32];
    __shared__ float redR[128], redC[128];

    const int tid  = threadIdx.x;
    const int lane = tid & 63;
    const int wid  = tid >> 6;
    const int srow = lane >> 2;
    const int scol = (lane & 3) * 8;
    const int wm = (wid & 1) * 64;
    const int wn = (wid >> 1) * 64;
    const int fm = lane & 31;
    const int fko = (lane >> 5) * 8;

    f32x16 acc[2][2];
#pragma unroll
    for (int i = 0; i < 2; i++)
#pragma unroll
        for (int j = 0; j < 2; j++)
#pragma unroll
            for (int r = 0; r < 16; r++) acc[i][j][r] = 0.f;

    for (int k0 = 0; k0 < EMB; k0 += 32) {
        __syncthreads();
#pragma unroll
        for (int u = 0; u < 2; u++) {
            const int unit = wid * 2 + u;
            const int row  = unit * 16 + srow;
            const size_t ga = (size_t)(l0 + row) * EMB + k0 + scol;
            const size_t gb = (size_t)(m0 + row) * EMB + k0 + scol;
            const int lo_off = unit * 512;
            g2lds16(Ah + ga, sAh + lo_off);
            g2lds16(Al + ga, sAl + lo_off);
            g2lds16(Bh + gb, sBh + lo_off);
            g2lds16(Bl + gb, sBl + lo_off);
        }
        __syncthreads();

        bf16x8 afh[2][2], afl[2][2], bfh[2][2], bfl[2][2];
#pragma unroll
        for (int i = 0; i < 2; i++)
#pragma unroll
            for (int ks = 0; ks < 2; ks++) {
                const int ra = (wm + i * 32 + fm) * 32 + ks * 16 + fko;
                afh[i][ks] = *(const bf16x8*)&sAh[ra];
                afl[i][ks] = *(const bf16x8*)&sAl[ra];
                const int rb = (wn + i * 32 + fm) * 32 + ks * 16 + fko;
                bfh[i][ks] = *(const bf16x8*)&sBh[rb];
                bfl[i][ks] = *(const bf16x8*)&sBl[rb];
            }
#pragma unroll
        for (int ks = 0; ks < 2; ks++)
#pragma unroll
            for (int i = 0; i < 2; i++)
#pragma unroll
                for (int j = 0; j < 2; j++) {
                    acc[i][j] = __builtin_amdgcn_mfma_f32_32x32x16_bf16(afh[i][ks], bfh[j][ks], acc[i][j], 0, 0, 0);
                    acc[i][j] = __builtin_amdgcn_mfma_f32_32x32x16_bf16(afh[i][ks], bfl[j][ks], acc[i][j], 0, 0, 0);
                    acc[i][j] = __builtin_amdgcn_mfma_f32_32x32x16_bf16(afl[i][ks], bfh[j][ks], acc[i][j], 0, 0, 0);
                }
    }

    if (tid < 128) { redR[tid] = 0.f; redC[tid] = 0.f; }
    __syncthreads();

    short* __restrict__ Ez = E + (size_t)hb * SEQ * SEQ;
    const int rhalf = (lane >> 5) * 4;
    float cj0 = 0.f, cj1 = 0.f;
#pragma unroll
    for (int i = 0; i < 2; i++)
#pragma unroll
        for (int r = 0; r < 16; r++) {
            const int row = wm + i * 32 + (r & 3) + 8 * (r >> 2) + rhalf;
            const short e0s = f2bf(expf(acc[i][0][r]));
            const short e1s = f2bf(expf(acc[i][1][r]));
            const float e0v = bf2f(e0s);
            const float e1v = bf2f(e1s);
            Ez[(size_t)(l0 + row) * SEQ + m0 + wn + fm]      = e0s;
            Ez[(size_t)(l0 + row) * SEQ + m0 + wn + 32 + fm] = e1s;
            float rv = e0v + e1v;
#pragma unroll
            for (int o = 16; o > 0; o >>= 1) rv += __shfl_xor(rv, o);
            if ((lane & 31) == 0) atomicAdd(&redR[row], rv);
            cj0 += e0v; cj1 += e1v;
        }
    cj0 += __shfl_xor(cj0, 32);
    cj1 += __shfl_xor(cj1, 32);
    if (lane < 32) {
        atomicAdd(&redC[wn + fm], cj0);
        atomicAdd(&redC[wn + 32 + fm], cj1);
    }
    __syncthreads();

    if (tid < 128) {
        atomicAdd(&Zr[hb * SEQ + l0 + tid], redR[tid]);
        atomicAdd(&Zc[hb * SEQ + m0 + tid], redC[tid]);
    }
}

// ---------------------------------------------------------------------------
// Pass 2 (memory-bound, bf16 E):
// S21[l] = sum_m E[l][m]/Zc[m]; S12[m] = sum_l E[l][m]/Zr[l]
// grid: (8, 32), block 256
// ---------------------------------------------------------------------------
__global__ __launch_bounds__(256) void reduce_pass(
    const short* __restrict__ E, const float* __restrict__ Zr,
    const float* __restrict__ Zc, float* __restrict__ S21, float* __restrict__ S12) {
    const int lblk = blockIdx.x;
    const int hb   = blockIdx.y;
    const int tid  = threadIdx.x;
    const int lane = tid & 63;
    const int wid  = tid >> 6;
    const short* __restrict__ Ez = E + (size_t)hb * SEQ * SEQ;

    __shared__ float colred[SEQ];
    for (int i = tid; i < SEQ; i += 256) colred[i] = 0.f;
    __syncthreads();

    float izc[2][8];
#pragma unroll
    for (int it = 0; it < 2; it++)
#pragma unroll
        for (int q = 0; q < 8; q++)
            izc[it][q] = 1.f / Zc[hb * SEQ + it * 512 + lane * 8 + q];

    float colacc[2][8];
#pragma unroll
    for (int it = 0; it < 2; it++)
#pragma unroll
        for (int q = 0; q < 8; q++) colacc[it][q] = 0.f;

    for (int rr = 0; rr < 32; rr++) {
        const int row = lblk * 128 + wid * 32 + rr;
        const float izr = 1.f / Zr[hb * SEQ + row];
        float rowsum = 0.f;
#pragma unroll
        for (int it = 0; it < 2; it++) {
            bf16x8 ev = *(const bf16x8*)&Ez[(size_t)row * SEQ + it * 512 + lane * 8];
#pragma unroll
            for (int q = 0; q < 8; q++) {
                const float e = bf2f(ev[q]);
                rowsum += e * izc[it][q];
                colacc[it][q] += e * izr;
            }
        }
#pragma unroll
        for (int o = 32; o > 0; o >>= 1) rowsum += __shfl_down(rowsum, o);
        if (lane == 0) S21[hb * SEQ + row] = rowsum;
    }
#pragma unroll
    for (int it = 0; it < 2; it++)
#pragma unroll
        for (int q = 0; q < 8; q++)
            atomicAdd(&colred[it * 512 + lane * 8 + q], colacc[it][q]);
    __syncthreads();
    for (int i = tid; i < SEQ; i += 256) atomicAdd(&S12[hb * SEQ + i], colred[i]);
}

// ---------------------------------------------------------------------------
__global__ __launch_bounds__(256) void fin_kernel(
    const float* __restrict__ S21, const float* __restrict__ S12,
    float* __restrict__ out) {
    const int z  = blockIdx.x;
    const int w  = z / (NHEAD * BSZ);
    const int hb = z % (NHEAD * BSZ);
    const float* __restrict__ src = (w == 0 ? S21 : S12) + (size_t)hb * SEQ;
    const int t = threadIdx.x;

    float s = 0.f;
    for (int i = t; i < SEQ; i += 256) s += src[i];
#pragma unroll
    for (int o = 32; o > 0; o >>= 1) s += __shfl_down(s, o);
    __shared__ float red[4];
    if ((t & 63) == 0) red[t >> 6] = s;
    __syncthreads();
    const float total = red[0] + red[1] + red[2] + red[3];
    const float inv = 1.f / (total + 1e-8f);
    for (int i = t; i < SEQ; i += 256)
        out[(size_t)z * SEQ + i] = src[i] * inv;
}

// ---------------------------------------------------------------------------
extern "C" void kernel_launch(void* const* d_in, const int* in_sizes, int n_in,
                              void* d_out, int out_size, void* d_ws, size_t ws_size,
                              hipStream_t stream) {
    const float* img1 = (const float*)d_in[0];
    const float* img2 = (const float*)d_in[1];
    const float* W    = (const float*)d_in[2];
    const float* bias = (const float*)d_in[3];
    float* out = (float*)d_out;

    const size_t QN = (size_t)2 * NHEAD * BSZ * SEQ * EMB;  // 33,554,432
    const size_t WN = (size_t)NHEAD * EMB * INP;            //  2,097,152
    const size_t CN = (size_t)8 * SEQ * INP;                // 16,777,216

    short* Qhi = (short*)d_ws;
    short* Qlo = Qhi + QN;
    short* Wth = Qlo + QN;
    short* Wtl = Wth + WN;
    short* iTh = Wtl + WN;
    short* iTl = iTh + CN;
    float* Q   = (float*)(iTl + CN);   // QN floats; region reused as bf16 E
    short* E   = (short*)Q;            // QN shorts (fits in QN floats)
    float* Zr  = Q + QN;
    float* Zc  = Zr + (size_t)NHEAD * BSZ * SEQ;
    float* S21 = Zc + (size_t)NHEAD * BSZ * SEQ;
    float* S12 = S21 + (size_t)NHEAD * BSZ * SEQ;

    zero_kernel<<<dim3(512), dim3(256), 0, stream>>>(Zr, 4 * NHEAD * BSZ * SEQ);

    conv_t<<<dim3(EMB / 32, INP / 32, NHEAD), dim3(256), 0, stream>>>(W, Wth, Wtl, EMB);

    for (int c = 0; c < 4; c++) {
        const int im = c >> 1;
        const int bbase = (c & 1) * 8;
        const float* img = (im == 0 ? img1 : img2) + (size_t)bbase * INP * SEQ;
        conv_t<<<dim3(SEQ / 32, INP / 32, 8), dim3(256), 0, stream>>>(img, iTh, iTl, SEQ);
        proj_mfma<<<dim3(512), dim3(256), 0, stream>>>(
            iTh, iTl, Wth, Wtl, bias, Q, im, bbase);
    }

    norm_split<<<dim3(SEQ, 2 * NHEAD * BSZ), dim3(64), 0, stream>>>(Q, Qhi, Qlo);

    attn_mfma<<<dim3(2048), dim3(256), 0, stream>>>(Qhi, Qlo, E, Zr, Zc);

    reduce_pass<<<dim3(8, NHEAD * BSZ), dim3(256), 0, stream>>>(E, Zr, Zc, S21, S12);

    fin_kernel<<<dim3(2 * NHEAD * BSZ), dim3(256), 0, stream>>>(S21, S12, out);
    (void)in_sizes; (void)n_in; (void)out_size; (void)ws_size;
}

// Round 4
// 931.671 us; speedup vs baseline: 1.0560x; 1.0560x over previous
//
#include <hip/hip_runtime.h>
#include <cstdint>
#include <cstddef>

#define INP 2048
#define EMB 512
#define NHEAD 2
#define BSZ 16
#define SEQ 1024
#define LAMBDA 10.0f

typedef __attribute__((ext_vector_type(8))) short bf16x8;
typedef __attribute__((ext_vector_type(4))) float f32x4;
typedef __attribute__((ext_vector_type(16))) float f32x16;

__device__ __forceinline__ short f2bf(float x) {
    union { float f; unsigned u; } v; v.f = x;
    unsigned r = v.u + 0x7fffu + ((v.u >> 16) & 1u);   // RTN-even
    return (short)(r >> 16);
}
__device__ __forceinline__ float bf2f(short h) {
    union { unsigned u; float f; } v; v.u = ((unsigned)(unsigned short)h) << 16;
    return v.f;
}
__device__ __forceinline__ void g2lds16(const void* g, void* l) {
    __builtin_amdgcn_global_load_lds(
        (const __attribute__((address_space(1))) unsigned int*)g,
        (__attribute__((address_space(3))) unsigned int*)l, 16, 0, 0);
}

// ---------------------------------------------------------------------------
__global__ __launch_bounds__(256) void zero_kernel(float* __restrict__ p, int n) {
    int i = blockIdx.x * 256 + threadIdx.x;
    if (i < n) p[i] = 0.f;
}

// ---------------------------------------------------------------------------
// Transpose+convert to k-major 16B slots:
// src slab [INP][L] fp32 -> hi/lo slot layout [kg=INP/8][L] (each slot = 8
// shorts = k 8-group for one row). Block: 32 d x 64 l tile.
// grid: (L/64, INP/32, slabs), block 256
// ---------------------------------------------------------------------------
__global__ __launch_bounds__(256) void conv_t(const float* __restrict__ src,
                                              short* __restrict__ hi,
                                              short* __restrict__ lo, int L) {
    const int l0 = blockIdx.x * 64;
    const int d0 = blockIdx.y * 32;
    const float* s = src + (size_t)blockIdx.z * INP * L;

    __shared__ float tl[32][65];
    const int t  = threadIdx.x;
    const int dr = t >> 3;
    const int f4 = (t & 7) * 4;

    float4 v0 = *(const float4*)&s[(size_t)(d0 + dr) * L + l0 + f4];
    float4 v1 = *(const float4*)&s[(size_t)(d0 + dr) * L + l0 + f4 + 32];
    tl[dr][f4 + 0] = v0.x; tl[dr][f4 + 1] = v0.y; tl[dr][f4 + 2] = v0.z; tl[dr][f4 + 3] = v0.w;
    tl[dr][f4 + 32] = v1.x; tl[dr][f4 + 33] = v1.y; tl[dr][f4 + 34] = v1.z; tl[dr][f4 + 35] = v1.w;
    __syncthreads();

    const int kgl = t >> 6;     // 0..3 (wave-uniform)
    const int l   = t & 63;
    bf16x8 hv8, lv8;
#pragma unroll
    for (int q = 0; q < 8; q++) {
        const float x = tl[kgl * 8 + q][l];
        const short h = f2bf(x);
        hv8[q] = h;
        lv8[q] = f2bf(x - bf2f(h));
    }
    const size_t slot = (size_t)blockIdx.z * (INP / 8) * L
                      + (size_t)(blockIdx.y * 4 + kgl) * L + l0 + l;
    *(bf16x8*)&hi[slot * 8] = hv8;
    *(bf16x8*)&lo[slot * 8] = lv8;
}

// ---------------------------------------------------------------------------
// Split-bf16 MFMA projection, 32x32x16, k-major LDS planes (conflict-free).
// A = iT_t slab [256 kg][1024 l], B = Wt_t [h][256 kg][512 e].
// grid 512 (XCD-swizzled), block 256.
// ---------------------------------------------------------------------------
__global__ __launch_bounds__(256) void proj_mfma(
    const short* __restrict__ Ahg, const short* __restrict__ Alg,
    const short* __restrict__ Bhg, const short* __restrict__ Blg,
    const float* __restrict__ bias, float* __restrict__ Q, int im, int bbase) {
    const int bid = blockIdx.x;
    const int xcd = bid & 7;
    const int s   = bid >> 3;          // 0..63
    const int zl  = xcd * 2 + (s >> 5);
    const int t2  = s & 31;
    const int et  = t2 & 3;            // e-tile inner: A-tile L2 reuse x4
    const int lt  = t2 >> 2;
    const int l0 = lt * 128;
    const int e0 = et * 128;
    const int h    = zl >> 3;
    const int bloc = zl & 7;
    const int z = (im * NHEAD + h) * BSZ + bbase + bloc;

    const short* __restrict__ Ah = Ahg + (size_t)bloc * SEQ * INP;
    const short* __restrict__ Al = Alg + (size_t)bloc * SEQ * INP;
    const short* __restrict__ Bh = Bhg + (size_t)h * EMB * INP;
    const short* __restrict__ Bl = Blg + (size_t)h * EMB * INP;

    __shared__ short sAh[4096], sAl[4096], sBh[4096], sBl[4096]; // 4 planes x 128 x 16B

    const int tid  = threadIdx.x;
    const int lane = tid & 63;
    const int wid  = tid >> 6;
    const int wm = (wid & 1) * 64;
    const int wn = (wid >> 1) * 64;
    const int fm = lane & 31;
    const int khl = lane >> 5;

    // staging assignment: wave wid owns one array entirely
    const short* gB = (wid == 0) ? Ah : (wid == 1) ? Al : (wid == 2) ? Bh : Bl;
    short* lB = (wid == 0) ? sAh : (wid == 1) ? sAl : (wid == 2) ? sBh : sBl;
    const int ps = (wid < 2) ? SEQ : EMB;   // plane stride in slots
    const int rb = (wid < 2) ? l0 : e0;

    f32x16 acc[2][2];
#pragma unroll
    for (int i = 0; i < 2; i++)
#pragma unroll
        for (int j = 0; j < 2; j++)
#pragma unroll
            for (int r = 0; r < 16; r++) acc[i][j][r] = 0.f;

    for (int k0 = 0; k0 < INP; k0 += 32) {
        const int k08 = k0 >> 3;
        __syncthreads();
#pragma unroll
        for (int v = 0; v < 8; v++) {
            const int g = v >> 1, hh = v & 1;
            g2lds16(gB + ((size_t)(k08 + g) * ps + rb + hh * 64 + lane) * 8,
                    lB + (g * 128 + hh * 64) * 8);
        }
        __syncthreads();

        bf16x8 afh[2][2], afl[2][2], bfh[2][2], bfl[2][2];
#pragma unroll
        for (int i = 0; i < 2; i++)
#pragma unroll
            for (int ks = 0; ks < 2; ks++) {
                const int ra = ((ks * 2 + khl) * 128 + wm + i * 32 + fm) * 8;
                afh[i][ks] = *(const bf16x8*)&sAh[ra];
                afl[i][ks] = *(const bf16x8*)&sAl[ra];
                const int rbi = ((ks * 2 + khl) * 128 + wn + i * 32 + fm) * 8;
                bfh[i][ks] = *(const bf16x8*)&sBh[rbi];
                bfl[i][ks] = *(const bf16x8*)&sBl[rbi];
            }
#pragma unroll
        for (int ks = 0; ks < 2; ks++)
#pragma unroll
            for (int i = 0; i < 2; i++)
#pragma unroll
                for (int j = 0; j < 2; j++) {
                    acc[i][j] = __builtin_amdgcn_mfma_f32_32x32x16_bf16(afh[i][ks], bfh[j][ks], acc[i][j], 0, 0, 0);
                    acc[i][j] = __builtin_amdgcn_mfma_f32_32x32x16_bf16(afh[i][ks], bfl[j][ks], acc[i][j], 0, 0, 0);
                    acc[i][j] = __builtin_amdgcn_mfma_f32_32x32x16_bf16(afl[i][ks], bfh[j][ks], acc[i][j], 0, 0, 0);
                }
    }

    float* __restrict__ Qz = Q + (size_t)z * SEQ * EMB;
    float bj[2];
#pragma unroll
    for (int j = 0; j < 2; j++) bj[j] = bias[h * EMB + e0 + wn + j * 32 + fm];
    const int rhalf = khl * 4;
#pragma unroll
    for (int i = 0; i < 2; i++)
#pragma unroll
        for (int r = 0; r < 16; r++) {
            const int row = l0 + wm + i * 32 + (r & 3) + 8 * (r >> 2) + rhalf;
#pragma unroll
            for (int j = 0; j < 2; j++) {
                const int col = e0 + wn + j * 32 + fm;
                Qz[(size_t)row * EMB + col] = acc[i][j][r] + bj[j];
            }
        }
}

// ---------------------------------------------------------------------------
// Row L2-norm of Q (fp32), fold LAMBDA into image-1 slabs, emit k-major
// bf16 hi/lo slots [z][kg=EMB/8][SEQ]. Block: 4 rows (1 wave each).
// grid: (SEQ/4, 64), block 256
// ---------------------------------------------------------------------------
__global__ __launch_bounds__(256) void norm_split(const float* __restrict__ Q,
                                                  short* __restrict__ Qhi,
                                                  short* __restrict__ Qlo) {
    const int z  = blockIdx.y;
    const int r0 = blockIdx.x * 4;
    const int t  = threadIdx.x;
    const int w    = t >> 6;
    const int lane = t & 63;
    const float* p = Q + ((size_t)z * SEQ + r0 + w) * EMB;

    float4 a = *(const float4*)&p[lane * 8];
    float4 b = *(const float4*)&p[lane * 8 + 4];
    float sq = a.x * a.x + a.y * a.y + a.z * a.z + a.w * a.w
             + b.x * b.x + b.y * b.y + b.z * b.z + b.w * b.w;
#pragma unroll
    for (int o = 32; o > 0; o >>= 1) sq += __shfl_xor(sq, o);
    float scale = 1.f / fmaxf(sqrtf(sq), 1e-12f);
    if (z < NHEAD * BSZ) scale *= LAMBDA;

    float v[8] = {a.x * scale, a.y * scale, a.z * scale, a.w * scale,
                  b.x * scale, b.y * scale, b.z * scale, b.w * scale};
    bf16x8 hv8, lv8;
#pragma unroll
    for (int q = 0; q < 8; q++) {
        const short hq = f2bf(v[q]);
        hv8[q] = hq;
        lv8[q] = f2bf(v[q] - bf2f(hq));
    }
    __shared__ short shi[64 * 4 * 8], slo[64 * 4 * 8];
    *(bf16x8*)&shi[(lane * 4 + w) * 8] = hv8;   // slot: kg=lane, row_local=w
    *(bf16x8*)&slo[(lane * 4 + w) * 8] = lv8;
    __syncthreads();

    // thread t -> slot t: kg = t>>2, row_local = t&3; coalesced 64B groups
    const int kg = t >> 2, rl = t & 3;
    const size_t dst = ((size_t)z * (EMB / 8) + kg) * SEQ + r0 + rl;
    *(bf16x8*)&Qhi[dst * 8] = *(const bf16x8*)&shi[t * 8];
    *(bf16x8*)&Qlo[dst * 8] = *(const bf16x8*)&slo[t * 8];
}

// ---------------------------------------------------------------------------
// Split-bf16 MFMA attention, 32x32x16, k-major LDS planes.
// Q*_t layout [z][64 kg][1024 rows]. E bf16 row-major.
// grid 2048 (XCD-swizzled), block 256.
// ---------------------------------------------------------------------------
__global__ __launch_bounds__(256) void attn_mfma(
    const short* __restrict__ Qhi, const short* __restrict__ Qlo,
    short* __restrict__ E, float* __restrict__ Zr, float* __restrict__ Zc) {
    const int bid = blockIdx.x;
    const int xcd = bid & 7;
    const int s   = bid >> 3;            // 0..255
    const int hb  = xcd * 4 + (s >> 6);
    const int t   = s & 63;
    const int lt  = t & 7;               // l-tile inner: m-tile L2 reuse x8
    const int mt  = t >> 3;
    const int l0 = lt * 128;
    const int m0 = mt * 128;

    const short* __restrict__ Ah = Qhi + (size_t)hb * SEQ * EMB;
    const short* __restrict__ Al = Qlo + (size_t)hb * SEQ * EMB;
    const short* __restrict__ Bh = Qhi + (size_t)(NHEAD * BSZ + hb) * SEQ * EMB;
    const short* __restrict__ Bl = Qlo + (size_t)(NHEAD * BSZ + hb) * SEQ * EMB;

    __shared__ short sAh[4096], sAl[4096], sBh[4096], sBl[4096];
    __shared__ float redR[128], redC[128];

    const int tid  = threadIdx.x;
    const int lane = tid & 63;
    const int wid  = tid >> 6;
    const int wm = (wid & 1) * 64;
    const int wn = (wid >> 1) * 64;
    const int fm = lane & 31;
    const int khl = lane >> 5;

    const short* gB = (wid == 0) ? Ah : (wid == 1) ? Al : (wid == 2) ? Bh : Bl;
    short* lB = (wid == 0) ? sAh : (wid == 1) ? sAl : (wid == 2) ? sBh : sBl;
    const int rb = (wid < 2) ? l0 : m0;

    f32x16 acc[2][2];
#pragma unroll
    for (int i = 0; i < 2; i++)
#pragma unroll
        for (int j = 0; j < 2; j++)
#pragma unroll
            for (int r = 0; r < 16; r++) acc[i][j][r] = 0.f;

    for (int k0 = 0; k0 < EMB; k0 += 32) {
        const int k08 = k0 >> 3;
        __syncthreads();
#pragma unroll
        for (int v = 0; v < 8; v++) {
            const int g = v >> 1, hh = v & 1;
            g2lds16(gB + ((size_t)(k08 + g) * SEQ + rb + hh * 64 + lane) * 8,
                    lB + (g * 128 + hh * 64) * 8);
        }
        __syncthreads();

        bf16x8 afh[2][2], afl[2][2], bfh[2][2], bfl[2][2];
#pragma unroll
        for (int i = 0; i < 2; i++)
#pragma unroll
            for (int ks = 0; ks < 2; ks++) {
                const int ra = ((ks * 2 + khl) * 128 + wm + i * 32 + fm) * 8;
                afh[i][ks] = *(const bf16x8*)&sAh[ra];
                afl[i][ks] = *(const bf16x8*)&sAl[ra];
                const int rbi = ((ks * 2 + khl) * 128 + wn + i * 32 + fm) * 8;
                bfh[i][ks] = *(const bf16x8*)&sBh[rbi];
                bfl[i][ks] = *(const bf16x8*)&sBl[rbi];
            }
#pragma unroll
        for (int ks = 0; ks < 2; ks++)
#pragma unroll
            for (int i = 0; i < 2; i++)
#pragma unroll
                for (int j = 0; j < 2; j++) {
                    acc[i][j] = __builtin_amdgcn_mfma_f32_32x32x16_bf16(afh[i][ks], bfh[j][ks], acc[i][j], 0, 0, 0);
                    acc[i][j] = __builtin_amdgcn_mfma_f32_32x32x16_bf16(afh[i][ks], bfl[j][ks], acc[i][j], 0, 0, 0);
                    acc[i][j] = __builtin_amdgcn_mfma_f32_32x32x16_bf16(afl[i][ks], bfh[j][ks], acc[i][j], 0, 0, 0);
                }
    }

    if (tid < 128) { redR[tid] = 0.f; redC[tid] = 0.f; }
    __syncthreads();

    short* __restrict__ Ez = E + (size_t)hb * SEQ * SEQ;
    const int rhalf = khl * 4;
    float cj0 = 0.f, cj1 = 0.f;
#pragma unroll
    for (int i = 0; i < 2; i++)
#pragma unroll
        for (int r = 0; r < 16; r++) {
            const int row = wm + i * 32 + (r & 3) + 8 * (r >> 2) + rhalf;
            const short e0s = f2bf(expf(acc[i][0][r]));
            const short e1s = f2bf(expf(acc[i][1][r]));
            const float e0v = bf2f(e0s);
            const float e1v = bf2f(e1s);
            Ez[(size_t)(l0 + row) * SEQ + m0 + wn + fm]      = e0s;
            Ez[(size_t)(l0 + row) * SEQ + m0 + wn + 32 + fm] = e1s;
            float rv = e0v + e1v;
#pragma unroll
            for (int o = 16; o > 0; o >>= 1) rv += __shfl_xor(rv, o);
            if ((lane & 31) == 0) atomicAdd(&redR[row], rv);
            cj0 += e0v; cj1 += e1v;
        }
    cj0 += __shfl_xor(cj0, 32);
    cj1 += __shfl_xor(cj1, 32);
    if (lane < 32) {
        atomicAdd(&redC[wn + fm], cj0);
        atomicAdd(&redC[wn + 32 + fm], cj1);
    }
    __syncthreads();

    if (tid < 128) {
        atomicAdd(&Zr[hb * SEQ + l0 + tid], redR[tid]);
        atomicAdd(&Zc[hb * SEQ + m0 + tid], redC[tid]);
    }
}

// ---------------------------------------------------------------------------
// Pass 2 (memory-bound, bf16 E):
// S21[l] = sum_m E[l][m]/Zc[m]; S12[m] = sum_l E[l][m]/Zr[l]
// ---------------------------------------------------------------------------
__global__ __launch_bounds__(256) void reduce_pass(
    const short* __restrict__ E, const float* __restrict__ Zr,
    const float* __restrict__ Zc, float* __restrict__ S21, float* __restrict__ S12) {
    const int lblk = blockIdx.x;
    const int hb   = blockIdx.y;
    const int tid  = threadIdx.x;
    const int lane = tid & 63;
    const int wid  = tid >> 6;
    const short* __restrict__ Ez = E + (size_t)hb * SEQ * SEQ;

    __shared__ float colred[SEQ];
    for (int i = tid; i < SEQ; i += 256) colred[i] = 0.f;
    __syncthreads();

    float izc[2][8];
#pragma unroll
    for (int it = 0; it < 2; it++)
#pragma unroll
        for (int q = 0; q < 8; q++)
            izc[it][q] = 1.f / Zc[hb * SEQ + it * 512 + lane * 8 + q];

    float colacc[2][8];
#pragma unroll
    for (int it = 0; it < 2; it++)
#pragma unroll
        for (int q = 0; q < 8; q++) colacc[it][q] = 0.f;

    for (int rr = 0; rr < 32; rr++) {
        const int row = lblk * 128 + wid * 32 + rr;
        const float izr = 1.f / Zr[hb * SEQ + row];
        float rowsum = 0.f;
#pragma unroll
        for (int it = 0; it < 2; it++) {
            bf16x8 ev = *(const bf16x8*)&Ez[(size_t)row * SEQ + it * 512 + lane * 8];
#pragma unroll
            for (int q = 0; q < 8; q++) {
                const float e = bf2f(ev[q]);
                rowsum += e * izc[it][q];
                colacc[it][q] += e * izr;
            }
        }
#pragma unroll
        for (int o = 32; o > 0; o >>= 1) rowsum += __shfl_down(rowsum, o);
        if (lane == 0) S21[hb * SEQ + row] = rowsum;
    }
#pragma unroll
    for (int it = 0; it < 2; it++)
#pragma unroll
        for (int q = 0; q < 8; q++)
            atomicAdd(&colred[it * 512 + lane * 8 + q], colacc[it][q]);
    __syncthreads();
    for (int i = tid; i < SEQ; i += 256) atomicAdd(&S12[hb * SEQ + i], colred[i]);
}

// ---------------------------------------------------------------------------
__global__ __launch_bounds__(256) void fin_kernel(
    const float* __restrict__ S21, const float* __restrict__ S12,
    float* __restrict__ out) {
    const int z  = blockIdx.x;
    const int w  = z / (NHEAD * BSZ);
    const int hb = z % (NHEAD * BSZ);
    const float* __restrict__ src = (w == 0 ? S21 : S12) + (size_t)hb * SEQ;
    const int t = threadIdx.x;

    float s = 0.f;
    for (int i = t; i < SEQ; i += 256) s += src[i];
#pragma unroll
    for (int o = 32; o > 0; o >>= 1) s += __shfl_down(s, o);
    __shared__ float red[4];
    if ((t & 63) == 0) red[t >> 6] = s;
    __syncthreads();
    const float total = red[0] + red[1] + red[2] + red[3];
    const float inv = 1.f / (total + 1e-8f);
    for (int i = t; i < SEQ; i += 256)
        out[(size_t)z * SEQ + i] = src[i] * inv;
}

// ---------------------------------------------------------------------------
extern "C" void kernel_launch(void* const* d_in, const int* in_sizes, int n_in,
                              void* d_out, int out_size, void* d_ws, size_t ws_size,
                              hipStream_t stream) {
    const float* img1 = (const float*)d_in[0];
    const float* img2 = (const float*)d_in[1];
    const float* W    = (const float*)d_in[2];
    const float* bias = (const float*)d_in[3];
    float* out = (float*)d_out;

    const size_t QN = (size_t)2 * NHEAD * BSZ * SEQ * EMB;  // 33,554,432
    const size_t WN = (size_t)NHEAD * EMB * INP;            //  2,097,152
    const size_t CN = (size_t)8 * SEQ * INP;                // 16,777,216

    short* Qhi = (short*)d_ws;
    short* Qlo = Qhi + QN;
    short* Wth = Qlo + QN;
    short* Wtl = Wth + WN;
    short* iTh = Wtl + WN;
    short* iTl = iTh + CN;
    float* Q   = (float*)(iTl + CN);   // QN floats; region reused as bf16 E
    short* E   = (short*)Q;
    float* Zr  = Q + QN;
    float* Zc  = Zr + (size_t)NHEAD * BSZ * SEQ;
    float* S21 = Zc + (size_t)NHEAD * BSZ * SEQ;
    float* S12 = S21 + (size_t)NHEAD * BSZ * SEQ;

    zero_kernel<<<dim3(512), dim3(256), 0, stream>>>(Zr, 4 * NHEAD * BSZ * SEQ);

    // W[h][d][e] -> k-major Wt_t[h][kg][e] hi/lo
    conv_t<<<dim3(EMB / 64, INP / 32, NHEAD), dim3(256), 0, stream>>>(W, Wth, Wtl, EMB);

    for (int c = 0; c < 4; c++) {
        const int im = c >> 1;
        const int bbase = (c & 1) * 8;
        const float* img = (im == 0 ? img1 : img2) + (size_t)bbase * INP * SEQ;
        conv_t<<<dim3(SEQ / 64, INP / 32, 8), dim3(256), 0, stream>>>(img, iTh, iTl, SEQ);
        proj_mfma<<<dim3(512), dim3(256), 0, stream>>>(
            iTh, iTl, Wth, Wtl, bias, Q, im, bbase);
    }

    norm_split<<<dim3(SEQ / 4, 2 * NHEAD * BSZ), dim3(256), 0, stream>>>(Q, Qhi, Qlo);

    attn_mfma<<<dim3(2048), dim3(256), 0, stream>>>(Qhi, Qlo, E, Zr, Zc);

    reduce_pass<<<dim3(8, NHEAD * BSZ), dim3(256), 0, stream>>>(E, Zr, Zc, S21, S12);

    fin_kernel<<<dim3(2 * NHEAD * BSZ), dim3(256), 0, stream>>>(S21, S12, out);
    (void)in_sizes; (void)n_in; (void)out_size; (void)ws_size;
}